// Round 4
// baseline (379.792 us; speedup 1.0000x reference)
//
#include <hip/hip_runtime.h>
#include <hip/hip_bf16.h>

#define GD 64
#define GC 256

typedef unsigned short u16;
typedef unsigned int u32;
typedef short bf16x8 __attribute__((ext_vector_type(8)));
typedef float f32x4 __attribute__((ext_vector_type(4)));

__device__ __forceinline__ u16 f2bf_rne(float f) {
    u32 u = __builtin_bit_cast(u32, f);
    u = (u + 0x7FFFu + ((u >> 16) & 1u)) >> 16;
    return (u16)u;
}

// round f32 to the exact bf16-representable value (RNE)
__device__ __forceinline__ float bfval(float f) {
    u32 u = __builtin_bit_cast(u32, f);
    u = (u + 0x7FFFu + ((u >> 16) & 1u)) & 0xFFFF0000u;
    return __builtin_bit_cast(float, u);
}

__device__ __forceinline__ void unpack8(uint4 r, float* w) {
    u32 v[4] = {r.x, r.y, r.z, r.w};
#pragma unroll
    for (int i = 0; i < 4; i++) {
        w[2 * i]     = __builtin_bit_cast(float, v[i] << 16);
        w[2 * i + 1] = __builtin_bit_cast(float, v[i] & 0xFFFF0000u);
    }
}

// max over the 7 window slots, packed to bf16 pairs (exact: values are bf16)
__device__ __forceinline__ uint4 maxpack(const float (&win)[7][8]) {
    u32 q[4];
#pragma unroll
    for (int i = 0; i < 4; i++) {
        u32 halves[2];
#pragma unroll
        for (int hh = 0; hh < 2; hh++) {
            int c = 2 * i + hh;
            float m01 = fmaxf(win[0][c], win[1][c]);
            float m23 = fmaxf(win[2][c], win[3][c]);
            float m45 = fmaxf(win[4][c], win[5][c]);
            float m = fmaxf(fmaxf(m01, m23), fmaxf(m45, win[6][c]));
            halves[hh] = __builtin_bit_cast(u32, m);
        }
        q[i] = (halves[0] >> 16) | (halves[1] & 0xFFFF0000u);
    }
    return make_uint4(q[0], q[1], q[2], q[3]);
}

// ---------------------------------------------------------------- init/build map
__global__ __launch_bounds__(256) void init_map(uint4* __restrict__ m) {
    int i = blockIdx.x * 256 + threadIdx.x;        // 65536 uint4 = 1 MB
    uint4 v;
    v.x = v.y = v.z = v.w = 0xFFFFFFFFu;
    m[i] = v;
}

__global__ __launch_bounds__(256) void build_map(const int* __restrict__ coords,
        int* __restrict__ map, int n) {
    int i = blockIdx.x * 256 + threadIdx.x;
    if (i < n) {
        int ix = coords[3 * i], iy = coords[3 * i + 1], iz = coords[3 * i + 2];
        map[(ix * GD + iy) * GD + iz] = i;         // coords unique (permutation)
    }
}

// ---------------------------------------------------------------- z pool (gather)
// Quarter-axis worker: outputs z in [Z0, Z0+16). Map row pre-loaded in mv
// (lane l holds m[2l], m[2l+1]); every mi is a width-32 shuffle with a
// compile-time source lane. All win[] indices compile-time.
template<int Z0>
__device__ __forceinline__ void pool_z_q(const float* __restrict__ fb,
        int2 mv, u16* __restrict__ p) {
    float win[7][8];
#pragma unroll
    for (int s = 0; s < 7; s++)
#pragma unroll
        for (int c = 0; c < 8; c++) win[s][c] = -INFINITY;

#pragma unroll
    for (int t = 0; t < 6; t++) {                  // preload inputs w = Z0-3..Z0+2
        const int w = Z0 - 3 + t;
        if (w >= 0) {
            int mi = __shfl((w & 1) ? mv.y : mv.x, (w >> 1) & 31, 32);
            if (mi >= 0) {
                const float4* f4 = (const float4*)(fb + (size_t)mi * GC);
                float4 a = f4[0], b = f4[1];
                float* ws = win[(w + 3) % 7];
                ws[0] = bfval(a.x); ws[1] = bfval(a.y);
                ws[2] = bfval(a.z); ws[3] = bfval(a.w);
                ws[4] = bfval(b.x); ws[5] = bfval(b.y);
                ws[6] = bfval(b.z); ws[7] = bfval(b.w);
            }
        }
    }

#pragma unroll
    for (int d = 0; d < 16; d++) {
        const int z = Z0 + d, w = z + 3, slot = (w + 3) % 7;
        bool live = false;
        if (w < 64) {
            int mi = __shfl((w & 1) ? mv.y : mv.x, (w >> 1) & 31, 32);
            if (mi >= 0) {
                live = true;
                const float4* f4 = (const float4*)(fb + (size_t)mi * GC);
                float4 a = f4[0], b = f4[1];
                float* ws = win[slot];
                ws[0] = bfval(a.x); ws[1] = bfval(a.y);
                ws[2] = bfval(a.z); ws[3] = bfval(a.w);
                ws[4] = bfval(b.x); ws[5] = bfval(b.y);
                ws[6] = bfval(b.z); ws[7] = bfval(b.w);
            }
        }
        if (!live) {
#pragma unroll
            for (int c = 0; c < 8; c++) win[slot][c] = -INFINITY;
        }
        *(uint4*)(p + (size_t)z * GC) = maxpack(win);
    }
}

__global__ __launch_bounds__(256) void pool_z_gather(const float* __restrict__ feats,
        const int* __restrict__ map, u16* __restrict__ grid) {
    int lane = threadIdx.x & 31;
    int g = blockIdx.x * 8 + (threadIdx.x >> 5);   // 0..16383 (2048 blocks)
    int L = g & 4095;                              // x*64+y
    int seg = g >> 12;                             // block-uniform
    int2 mv = ((const int2*)(map + L * GD))[lane]; // lane l: m[2l], m[2l+1]
    const float* fb = feats + lane * 8;
    u16* p = grid + (size_t)L * GD * GC + lane * 8;
    if      (seg == 0) pool_z_q<0>(fb, mv, p);
    else if (seg == 1) pool_z_q<16>(fb, mv, p);
    else if (seg == 2) pool_z_q<32>(fb, mv, p);
    else               pool_z_q<48>(fb, mv, p);
}

// ---------------------------------------------------------------- dense line pool
// (y pass, out of place). Outputs axis index in [A0, A0+16), halo reads only.
template<int A0>
__device__ __forceinline__ void pool_line_dense(const u16* __restrict__ ip,
        u16* __restrict__ op, size_t stepEl) {
    float win[7][8];
#pragma unroll
    for (int s = 0; s < 7; s++)
#pragma unroll
        for (int c = 0; c < 8; c++) win[s][c] = -INFINITY;

#pragma unroll
    for (int t = 0; t < 6; t++) {
        const int w = A0 - 3 + t;
        if (w >= 0) {
            uint4 r = *(const uint4*)(ip + (size_t)w * stepEl);
            unpack8(r, win[(w + 3) % 7]);
        }
    }
#pragma unroll
    for (int d = 0; d < 16; d++) {
        const int a = A0 + d, w = a + 3, slot = (w + 3) % 7;
        if (w < 64) {
            uint4 r = *(const uint4*)(ip + (size_t)w * stepEl);
            unpack8(r, win[slot]);
        } else {
#pragma unroll
            for (int c = 0; c < 8; c++) win[slot][c] = -INFINITY;
        }
        *(uint4*)(op + (size_t)a * stepEl) = maxpack(win);
    }
}

__global__ __launch_bounds__(256) void pool_y(const u16* __restrict__ gin,
        u16* __restrict__ gout) {
    int lane = threadIdx.x & 31;
    int g = blockIdx.x * 8 + (threadIdx.x >> 5);   // 0..16383 (2048 blocks)
    int L = g & 4095;                              // x*64+z
    int seg = g >> 12;
    int x = L >> 6, z = L & 63;
    size_t base = ((size_t)x * GD * GD + z) * GC + lane * 8;
    size_t stepEl = (size_t)GD * GC;               // +1 in y
    if      (seg == 0) pool_line_dense<0>(gin + base, gout + base, stepEl);
    else if (seg == 1) pool_line_dense<16>(gin + base, gout + base, stepEl);
    else if (seg == 2) pool_line_dense<32>(gin + base, gout + base, stepEl);
    else               pool_line_dense<48>(gin + base, gout + base, stepEl);
}

// ---------------------------------------------------------------- x pool + compact
template<int X0>
__device__ __forceinline__ void pool_x_q(const u16* __restrict__ ip, size_t stepEl,
        int m0, int m1, u16* __restrict__ P, int chunkoff) {
    float win[7][8];
#pragma unroll
    for (int s = 0; s < 7; s++)
#pragma unroll
        for (int c = 0; c < 8; c++) win[s][c] = -INFINITY;

#pragma unroll
    for (int t = 0; t < 6; t++) {
        const int w = X0 - 3 + t;
        if (w >= 0) {
            uint4 r = *(const uint4*)(ip + (size_t)w * stepEl);
            unpack8(r, win[(w + 3) % 7]);
        }
    }
#pragma unroll
    for (int d = 0; d < 16; d++) {
        const int a = X0 + d, w = a + 3, slot = (w + 3) % 7;
        if (w < 64) {
            uint4 r = *(const uint4*)(ip + (size_t)w * stepEl);
            unpack8(r, win[slot]);
        } else {
#pragma unroll
            for (int c = 0; c < 8; c++) win[slot][c] = -INFINITY;
        }
        int mi = __shfl((a < 32) ? m0 : m1, a & 31, 32);
        if (mi >= 0)
            *(uint4*)(P + (size_t)mi * GC + chunkoff) = maxpack(win);
    }
}

__global__ __launch_bounds__(256) void pool_x_compact(const u16* __restrict__ gin,
        const int* __restrict__ map, u16* __restrict__ P) {
    int lane = threadIdx.x & 31;
    int g = blockIdx.x * 8 + (threadIdx.x >> 5);   // 0..16383 (2048 blocks)
    int L = g & 4095;                              // y*64+z
    int seg = g >> 12;
    int m0 = map[L + lane * GD * GD];              // x = lane
    int m1 = map[L + (lane + 32) * GD * GD];       // x = lane+32
    size_t base = (size_t)L * GC + lane * 8;
    size_t stepEl = (size_t)GD * GD * GC;          // +1 in x
    if      (seg == 0) pool_x_q<0>(gin + base, stepEl, m0, m1, P, lane * 8);
    else if (seg == 1) pool_x_q<16>(gin + base, stepEl, m0, m1, P, lane * 8);
    else if (seg == 2) pool_x_q<32>(gin + base, stepEl, m0, m1, P, lane * 8);
    else               pool_x_q<48>(gin + base, stepEl, m0, m1, P, lane * 8);
}

// ---------------------------------------------------------------- weight prep
__global__ __launch_bounds__(256) void prep_weights(const float* __restrict__ W1,
        const float* __restrict__ W2, u16* __restrict__ img1, u16* __restrict__ img2) {
    int t = blockIdx.x * 256 + threadIdx.x;   // 0..65535
    if (t < 32768) {
        int h = t >> 14, nn = (t >> 8) & 63, chunk = (t >> 3) & 31, j = t & 7;
        int k = chunk * 8 + j;
        img1[(h << 14) + nn * 256 + (((chunk ^ (nn & 7)) << 3) | j)] =
            f2bf_rne(W1[k * 128 + h * 64 + nn]);
    } else {
        int t2 = t - 32768;
        int h = t2 >> 14, nn = (t2 >> 7) & 127, chunk = (t2 >> 3) & 15, j = t2 & 7;
        int k = chunk * 8 + j;
        img2[(h << 14) + nn * 128 + (((chunk ^ (nn & 7)) << 3) | j)] =
            f2bf_rne(W2[k * 256 + h * 128 + nn]);
    }
}

// ---------------------------------------------------------------- GEMM1 (half-N)
__global__ __launch_bounds__(256, 4) void gemm1_kernel(const u16* __restrict__ P,
        const u16* __restrict__ img1, u16* __restrict__ H, int n, int nrb) {
    __shared__ __align__(16) u16 w1t[64 * 256];   // 32768 B; reused as hbuf
    int h = blockIdx.x >= nrb;
    int rb = blockIdx.x - (h ? nrb : 0);
    int tid = threadIdx.x;

    const uint4* src = (const uint4*)(img1 + (h << 14));
    uint4* dst = (uint4*)w1t;
#pragma unroll
    for (int i = 0; i < 8; i++) dst[i * 256 + tid] = src[i * 256 + tid];

    int wave = tid >> 6, lane = tid & 63, m16 = lane & 15, quad = lane >> 4;
    int row_a = rb * 64 + wave * 16 + m16;
    int ra = min(row_a, n - 1);
    const u16* yrow = P + (size_t)ra * GC;
    bf16x8 afr[8];
#pragma unroll
    for (int kk = 0; kk < 8; kk++)
        afr[kk] = *(const bf16x8*)(yrow + kk * 32 + quad * 8);
    __syncthreads();

    f32x4 acc[4];
#pragma unroll
    for (int t = 0; t < 4; t++) acc[t] = (f32x4){0.f, 0.f, 0.f, 0.f};
#pragma unroll
    for (int kk = 0; kk < 8; kk++) {
        int chunk = kk * 4 + quad;
#pragma unroll
        for (int t = 0; t < 4; t++) {
            int r = t * 16 + m16;
            bf16x8 b = *(const bf16x8*)&w1t[r * 256 + ((chunk ^ (r & 7)) << 3)];
            acc[t] = __builtin_amdgcn_mfma_f32_16x16x32_bf16(afr[kk], b, acc[t], 0, 0, 0);
        }
    }
    __syncthreads();   // w1t dead; reuse as hbuf

    u16* hbuf = w1t;
#pragma unroll
    for (int t = 0; t < 4; t++) {
        int col = t * 16 + m16;
        int c8 = col >> 3, j = col & 7;
#pragma unroll
        for (int rr = 0; rr < 4; rr++) {
            int row_l = wave * 16 + quad * 4 + rr;
            float hv = fmaxf(acc[t][rr], 0.0f);
            hbuf[row_l * 64 + (((c8 ^ (row_l & 7)) << 3) | j)] = f2bf_rne(hv);
        }
    }
    __syncthreads();
#pragma unroll
    for (int i = 0; i < 2; i++) {
        int cid = i * 256 + tid;            // 0..511 chunks of 8
        int row_l = cid >> 3, c8 = cid & 7;
        int grow = rb * 64 + row_l;
        if (grow < n) {
            bf16x8 v = *(const bf16x8*)&hbuf[row_l * 64 + ((c8 ^ (row_l & 7)) << 3)];
            *(bf16x8*)&H[(size_t)grow * 128 + h * 64 + c8 * 8] = v;
        }
    }
}

// ---------------------------------------------------------------- GEMM2 (half-N)
__global__ __launch_bounds__(256, 4) void gemm2_kernel(const u16* __restrict__ H,
        const u16* __restrict__ img2, const float* __restrict__ feats,
        float* __restrict__ out, int n, int nrb) {
    __shared__ __align__(16) char smem[64 * 140 * 4];   // 35840 B
    u16* w2t = (u16*)smem;
    float* zbuf = (float*)smem;
    int h = blockIdx.x >= nrb;
    int rb = blockIdx.x - (h ? nrb : 0);
    int tid = threadIdx.x;

    const uint4* src = (const uint4*)(img2 + (h << 14));
    uint4* dst = (uint4*)w2t;
#pragma unroll
    for (int i = 0; i < 8; i++) dst[i * 256 + tid] = src[i * 256 + tid];

    int wave = tid >> 6, lane = tid & 63, m16 = lane & 15, quad = lane >> 4;
    int row_a = rb * 64 + wave * 16 + m16;
    int ra = min(row_a, n - 1);
    const u16* hrow = H + (size_t)ra * 128;
    bf16x8 afr[4];
#pragma unroll
    for (int kk = 0; kk < 4; kk++)
        afr[kk] = *(const bf16x8*)(hrow + kk * 32 + quad * 8);
    __syncthreads();

    f32x4 acc[8];
#pragma unroll
    for (int t = 0; t < 8; t++) acc[t] = (f32x4){0.f, 0.f, 0.f, 0.f};
#pragma unroll
    for (int kk = 0; kk < 4; kk++) {
        int chunk = kk * 4 + quad;
#pragma unroll
        for (int t = 0; t < 8; t++) {
            int nn = t * 16 + m16;
            bf16x8 b = *(const bf16x8*)&w2t[nn * 128 + ((chunk ^ (nn & 7)) << 3)];
            acc[t] = __builtin_amdgcn_mfma_f32_16x16x32_bf16(afr[kk], b, acc[t], 0, 0, 0);
        }
    }
    __syncthreads();   // w2t dead; write logits into zbuf

#pragma unroll
    for (int t = 0; t < 8; t++) {
        int col = t * 16 + m16;
#pragma unroll
        for (int rr = 0; rr < 4; rr++) {
            int row_l = wave * 16 + quad * 4 + rr;
            zbuf[row_l * 140 + col] = acc[t][rr];
        }
    }
    __syncthreads();
#pragma unroll
    for (int i = 0; i < 8; i++) {
        int f = i * 256 + tid;              // 0..2047 float4s
        int row_l = f >> 5, c4 = f & 31;
        int grow = rb * 64 + row_l;
        if (grow < n) {
            f32x4 z = *(const f32x4*)&zbuf[row_l * 140 + c4 * 4];
            size_t o = (size_t)grow * 256 + h * 128 + c4 * 4;
            f32x4 ft = *(const f32x4*)&feats[o];
            f32x4 r;
#pragma unroll
            for (int c = 0; c < 4; c++)
                r[c] = ft[c] / (1.0f + __expf(-z[c]));
            *(f32x4*)&out[o] = r;
        }
    }
}

// ---------------------------------------------------------------- launch
extern "C" void kernel_launch(void* const* d_in, const int* in_sizes, int n_in,
                              void* d_out, int out_size, void* d_ws, size_t ws_size,
                              hipStream_t stream) {
    const float* feats = (const float*)d_in[0];
    const int* coords = (const int*)d_in[1];
    const float* W1 = (const float*)d_in[2];
    const float* W2 = (const float*)d_in[3];
    float* out = (float*)d_out;

    int n = in_sizes[1] / 3;                       // 100000 points

    size_t grid_bytes = (size_t)GD * GD * GD * GC * 2;          // 134,217,728
    size_t P_bytes = (size_t)n * GC * 2;                        //  51,200,000
    size_t H_bytes = (size_t)n * 128 * 2;                       //  25,600,000
    u16* grid = (u16*)d_ws;                                     // never initialized
    u16* grid2 = (u16*)((char*)d_ws + grid_bytes);              // y-pass output
    u16* P = (u16*)((char*)d_ws + 2 * grid_bytes);
    u16* H = (u16*)((char*)d_ws + 2 * grid_bytes + P_bytes);
    int* map = (int*)((char*)d_ws + 2 * grid_bytes + P_bytes + H_bytes);
    u16* img1 = (u16*)((char*)map + (size_t)GD * GD * GD * 4);  // +1 MB
    u16* img2 = img1 + 32768;

    init_map<<<256, 256, 0, stream>>>((uint4*)map);
    prep_weights<<<256, 256, 0, stream>>>(W1, W2, img1, img2);
    build_map<<<(n + 255) / 256, 256, 0, stream>>>(coords, map, n);

    pool_z_gather<<<2048, 256, 0, stream>>>(feats, map, grid);     // z (gather, x4 split)
    pool_y<<<2048, 256, 0, stream>>>(grid, grid2);                 // y (out of place, x4)
    pool_x_compact<<<2048, 256, 0, stream>>>(grid2, map, P);       // x -> compact (x4)

    int nrb = (n + 63) / 64;
    gemm1_kernel<<<2 * nrb, 256, 0, stream>>>(P, img1, H, n, nrb);
    gemm2_kernel<<<2 * nrb, 256, 0, stream>>>(H, img2, feats, out, n, nrb);
}

// Round 5
// 369.857 us; speedup vs baseline: 1.0269x; 1.0269x over previous
//
#include <hip/hip_runtime.h>
#include <hip/hip_bf16.h>

#define GD 64
#define GC 256

typedef unsigned short u16;
typedef unsigned int u32;
typedef short bf16x8 __attribute__((ext_vector_type(8)));
typedef float f32x4 __attribute__((ext_vector_type(4)));

__device__ __forceinline__ u16 f2bf_rne(float f) {
    u32 u = __builtin_bit_cast(u32, f);
    u = (u + 0x7FFFu + ((u >> 16) & 1u)) >> 16;
    return (u16)u;
}

// round f32 to the exact bf16-representable value (RNE)
__device__ __forceinline__ float bfval(float f) {
    u32 u = __builtin_bit_cast(u32, f);
    u = (u + 0x7FFFu + ((u >> 16) & 1u)) & 0xFFFF0000u;
    return __builtin_bit_cast(float, u);
}

__device__ __forceinline__ void unpack8(uint4 r, float* w) {
    u32 v[4] = {r.x, r.y, r.z, r.w};
#pragma unroll
    for (int i = 0; i < 4; i++) {
        w[2 * i]     = __builtin_bit_cast(float, v[i] << 16);
        w[2 * i + 1] = __builtin_bit_cast(float, v[i] & 0xFFFF0000u);
    }
}

// max over the 7 window slots, packed to bf16 pairs (exact: values are bf16)
__device__ __forceinline__ uint4 maxpack(const float (&win)[7][8]) {
    u32 q[4];
#pragma unroll
    for (int i = 0; i < 4; i++) {
        u32 halves[2];
#pragma unroll
        for (int hh = 0; hh < 2; hh++) {
            int c = 2 * i + hh;
            float m01 = fmaxf(win[0][c], win[1][c]);
            float m23 = fmaxf(win[2][c], win[3][c]);
            float m45 = fmaxf(win[4][c], win[5][c]);
            float m = fmaxf(fmaxf(m01, m23), fmaxf(m45, win[6][c]));
            halves[hh] = __builtin_bit_cast(u32, m);
        }
        q[i] = (halves[0] >> 16) | (halves[1] & 0xFFFF0000u);
    }
    return make_uint4(q[0], q[1], q[2], q[3]);
}

// ---------------------------------------------------------------- init/build map
__global__ __launch_bounds__(256) void init_map(uint4* __restrict__ m) {
    int i = blockIdx.x * 256 + threadIdx.x;        // 65536 uint4 = 1 MB
    uint4 v;
    v.x = v.y = v.z = v.w = 0xFFFFFFFFu;
    m[i] = v;
}

__global__ __launch_bounds__(256) void build_map(const int* __restrict__ coords,
        int* __restrict__ map, int n) {
    int i = blockIdx.x * 256 + threadIdx.x;
    if (i < n) {
        int ix = coords[3 * i], iy = coords[3 * i + 1], iz = coords[3 * i + 2];
        map[(ix * GD + iy) * GD + iz] = i;         // coords unique (permutation)
    }
}

// ---------------------------------------------------------------- z pool (gather)
// Software-pipelined: circular PF-deep prefetch buffer (compile-time indices),
// UNCONDITIONAL clamped loads (mi<0 -> row 0, selected to -inf at consume) so
// the compiler can keep PF loads in flight instead of vmcnt(0) every step.
// Outputs z in [Z0, Z0+32); inputs t=0..37, w = Z0-3+t.
template<int Z0>
__device__ __forceinline__ void pool_z_pipe(const float* __restrict__ fb,
        int2 mv, u16* __restrict__ p) {
    constexpr int PF = 4, IN = 38;
    float win[7][8];
#pragma unroll
    for (int s = 0; s < 7; s++)
#pragma unroll
        for (int c = 0; c < 8; c++) win[s][c] = -INFINITY;

    float4 pa[PF], pb[PF];
    int pm[PF];

#pragma unroll
    for (int t = 0; t < PF; t++) {                 // prologue: fill pipeline
        const int w = Z0 - 3 + t;
        if (w >= 0 && w < 64) {
            int mi = __shfl((w & 1) ? mv.y : mv.x, (w >> 1) & 31, 32);
            pm[t % PF] = mi;
            const float4* f4 = (const float4*)(fb + (size_t)max(mi, 0) * GC);
            pa[t % PF] = f4[0];
            pb[t % PF] = f4[1];
        }
    }

#pragma unroll
    for (int t = 0; t < IN; t++) {
        const int w = Z0 - 3 + t, slot = (w + 3) % 7;
        // consume buf[t%PF] -> window slot
        if (w >= 0 && w < 64) {
            bool sel = pm[t % PF] >= 0;
            float4 a = pa[t % PF], b = pb[t % PF];
            win[slot][0] = bfval(sel ? a.x : -INFINITY);
            win[slot][1] = bfval(sel ? a.y : -INFINITY);
            win[slot][2] = bfval(sel ? a.z : -INFINITY);
            win[slot][3] = bfval(sel ? a.w : -INFINITY);
            win[slot][4] = bfval(sel ? b.x : -INFINITY);
            win[slot][5] = bfval(sel ? b.y : -INFINITY);
            win[slot][6] = bfval(sel ? b.z : -INFINITY);
            win[slot][7] = bfval(sel ? b.w : -INFINITY);
        } else {
#pragma unroll
            for (int c = 0; c < 8; c++) win[slot][c] = -INFINITY;
        }
        // issue load t+PF into the slot just freed
        const int tn = t + PF;
        if (tn < IN) {
            const int wn = Z0 - 3 + tn;
            if (wn >= 0 && wn < 64) {
                int mi = __shfl((wn & 1) ? mv.y : mv.x, (wn >> 1) & 31, 32);
                pm[tn % PF] = mi;
                const float4* f4 = (const float4*)(fb + (size_t)max(mi, 0) * GC);
                pa[tn % PF] = f4[0];
                pb[tn % PF] = f4[1];
            }
        }
        // emit output z = Z0 + t - 6 once its last input (w = z+3) is in
        if (t >= 6) {
            const int z = Z0 + t - 6;
            *(uint4*)(p + (size_t)z * GC) = maxpack(win);
        }
    }
}

__global__ __launch_bounds__(256, 4) void pool_z_gather(const float* __restrict__ feats,
        const int* __restrict__ map, u16* __restrict__ grid) {
    int lane = threadIdx.x & 31;
    int g = blockIdx.x * 8 + (threadIdx.x >> 5);   // 0..8191 (1024 blocks)
    int L = g & 4095;                              // x*64+y
    int2 mv = ((const int2*)(map + L * GD))[lane]; // lane l: m[2l], m[2l+1]
    const float* fb = feats + lane * 8;
    u16* p = grid + (size_t)L * GD * GC + lane * 8;
    if (g < 4096) pool_z_pipe<0>(fb, mv, p);       // block-uniform branch
    else          pool_z_pipe<32>(fb, mv, p);
}

// ---------------------------------------------------------------- dense line pool
// (y pass, out of place). Same PF-deep pipeline; loads compile-time
// unconditional. Outputs axis index in [A0, A0+32).
template<int A0>
__device__ __forceinline__ void pool_line_pipe(const u16* __restrict__ ip,
        u16* __restrict__ op, size_t stepEl) {
    constexpr int PF = 6, IN = 38;
    float win[7][8];
#pragma unroll
    for (int s = 0; s < 7; s++)
#pragma unroll
        for (int c = 0; c < 8; c++) win[s][c] = -INFINITY;

    uint4 buf[PF];
#pragma unroll
    for (int t = 0; t < PF; t++) {
        const int w = A0 - 3 + t;
        if (w >= 0 && w < 64)
            buf[t % PF] = *(const uint4*)(ip + (size_t)w * stepEl);
    }

#pragma unroll
    for (int t = 0; t < IN; t++) {
        const int w = A0 - 3 + t, slot = (w + 3) % 7;
        if (w >= 0 && w < 64) {
            unpack8(buf[t % PF], win[slot]);
        } else {
#pragma unroll
            for (int c = 0; c < 8; c++) win[slot][c] = -INFINITY;
        }
        const int tn = t + PF;
        if (tn < IN) {
            const int wn = A0 - 3 + tn;
            if (wn >= 0 && wn < 64)
                buf[tn % PF] = *(const uint4*)(ip + (size_t)wn * stepEl);
        }
        if (t >= 6) {
            const int a = A0 + t - 6;
            *(uint4*)(op + (size_t)a * stepEl) = maxpack(win);
        }
    }
}

__global__ __launch_bounds__(256, 4) void pool_y(const u16* __restrict__ gin,
        u16* __restrict__ gout) {
    int lane = threadIdx.x & 31;
    int g = blockIdx.x * 8 + (threadIdx.x >> 5);   // 0..8191 (1024 blocks)
    int L = g & 4095;                              // x*64+z
    int x = L >> 6, z = L & 63;
    size_t base = ((size_t)x * GD * GD + z) * GC + lane * 8;
    size_t stepEl = (size_t)GD * GC;               // +1 in y
    if (g < 4096) pool_line_pipe<0>(gin + base, gout + base, stepEl);
    else          pool_line_pipe<32>(gin + base, gout + base, stepEl);
}

// ---------------------------------------------------------------- x pool + compact
// Same pipeline; store gated (store-side branch only, loads unconditional).
template<int X0>
__device__ __forceinline__ void pool_x_pipe(const u16* __restrict__ ip, size_t stepEl,
        int m0, int m1, u16* __restrict__ P, int chunkoff) {
    constexpr int PF = 6, IN = 38;
    float win[7][8];
#pragma unroll
    for (int s = 0; s < 7; s++)
#pragma unroll
        for (int c = 0; c < 8; c++) win[s][c] = -INFINITY;

    uint4 buf[PF];
#pragma unroll
    for (int t = 0; t < PF; t++) {
        const int w = X0 - 3 + t;
        if (w >= 0 && w < 64)
            buf[t % PF] = *(const uint4*)(ip + (size_t)w * stepEl);
    }

#pragma unroll
    for (int t = 0; t < IN; t++) {
        const int w = X0 - 3 + t, slot = (w + 3) % 7;
        if (w >= 0 && w < 64) {
            unpack8(buf[t % PF], win[slot]);
        } else {
#pragma unroll
            for (int c = 0; c < 8; c++) win[slot][c] = -INFINITY;
        }
        const int tn = t + PF;
        if (tn < IN) {
            const int wn = X0 - 3 + tn;
            if (wn >= 0 && wn < 64)
                buf[tn % PF] = *(const uint4*)(ip + (size_t)wn * stepEl);
        }
        if (t >= 6) {
            const int a = X0 + t - 6;
            int mi = __shfl((a < 32) ? m0 : m1, a & 31, 32);
            if (mi >= 0)
                *(uint4*)(P + (size_t)mi * GC + chunkoff) = maxpack(win);
        }
    }
}

__global__ __launch_bounds__(256, 4) void pool_x_compact(const u16* __restrict__ gin,
        const int* __restrict__ map, u16* __restrict__ P) {
    int lane = threadIdx.x & 31;
    int g = blockIdx.x * 8 + (threadIdx.x >> 5);   // 0..8191 (1024 blocks)
    int L = g & 4095;                              // y*64+z
    int m0 = map[L + lane * GD * GD];              // x = lane
    int m1 = map[L + (lane + 32) * GD * GD];       // x = lane+32
    size_t base = (size_t)L * GC + lane * 8;
    size_t stepEl = (size_t)GD * GD * GC;          // +1 in x
    if (g < 4096) pool_x_pipe<0>(gin + base, stepEl, m0, m1, P, lane * 8);
    else          pool_x_pipe<32>(gin + base, stepEl, m0, m1, P, lane * 8);
}

// ---------------------------------------------------------------- weight prep
__global__ __launch_bounds__(256) void prep_weights(const float* __restrict__ W1,
        const float* __restrict__ W2, u16* __restrict__ img1, u16* __restrict__ img2) {
    int t = blockIdx.x * 256 + threadIdx.x;   // 0..65535
    if (t < 32768) {
        int h = t >> 14, nn = (t >> 8) & 63, chunk = (t >> 3) & 31, j = t & 7;
        int k = chunk * 8 + j;
        img1[(h << 14) + nn * 256 + (((chunk ^ (nn & 7)) << 3) | j)] =
            f2bf_rne(W1[k * 128 + h * 64 + nn]);
    } else {
        int t2 = t - 32768;
        int h = t2 >> 14, nn = (t2 >> 7) & 127, chunk = (t2 >> 3) & 15, j = t2 & 7;
        int k = chunk * 8 + j;
        img2[(h << 14) + nn * 128 + (((chunk ^ (nn & 7)) << 3) | j)] =
            f2bf_rne(W2[k * 256 + h * 128 + nn]);
    }
}

// ---------------------------------------------------------------- GEMM1 (half-N)
__global__ __launch_bounds__(256, 4) void gemm1_kernel(const u16* __restrict__ P,
        const u16* __restrict__ img1, u16* __restrict__ H, int n, int nrb) {
    __shared__ __align__(16) u16 w1t[64 * 256];   // 32768 B; reused as hbuf
    int h = blockIdx.x >= nrb;
    int rb = blockIdx.x - (h ? nrb : 0);
    int tid = threadIdx.x;

    const uint4* src = (const uint4*)(img1 + (h << 14));
    uint4* dst = (uint4*)w1t;
#pragma unroll
    for (int i = 0; i < 8; i++) dst[i * 256 + tid] = src[i * 256 + tid];

    int wave = tid >> 6, lane = tid & 63, m16 = lane & 15, quad = lane >> 4;
    int row_a = rb * 64 + wave * 16 + m16;
    int ra = min(row_a, n - 1);
    const u16* yrow = P + (size_t)ra * GC;
    bf16x8 afr[8];
#pragma unroll
    for (int kk = 0; kk < 8; kk++)
        afr[kk] = *(const bf16x8*)(yrow + kk * 32 + quad * 8);
    __syncthreads();

    f32x4 acc[4];
#pragma unroll
    for (int t = 0; t < 4; t++) acc[t] = (f32x4){0.f, 0.f, 0.f, 0.f};
#pragma unroll
    for (int kk = 0; kk < 8; kk++) {
        int chunk = kk * 4 + quad;
#pragma unroll
        for (int t = 0; t < 4; t++) {
            int r = t * 16 + m16;
            bf16x8 b = *(const bf16x8*)&w1t[r * 256 + ((chunk ^ (r & 7)) << 3)];
            acc[t] = __builtin_amdgcn_mfma_f32_16x16x32_bf16(afr[kk], b, acc[t], 0, 0, 0);
        }
    }
    __syncthreads();   // w1t dead; reuse as hbuf

    u16* hbuf = w1t;
#pragma unroll
    for (int t = 0; t < 4; t++) {
        int col = t * 16 + m16;
        int c8 = col >> 3, j = col & 7;
#pragma unroll
        for (int rr = 0; rr < 4; rr++) {
            int row_l = wave * 16 + quad * 4 + rr;
            float hv = fmaxf(acc[t][rr], 0.0f);
            hbuf[row_l * 64 + (((c8 ^ (row_l & 7)) << 3) | j)] = f2bf_rne(hv);
        }
    }
    __syncthreads();
#pragma unroll
    for (int i = 0; i < 2; i++) {
        int cid = i * 256 + tid;            // 0..511 chunks of 8
        int row_l = cid >> 3, c8 = cid & 7;
        int grow = rb * 64 + row_l;
        if (grow < n) {
            bf16x8 v = *(const bf16x8*)&hbuf[row_l * 64 + ((c8 ^ (row_l & 7)) << 3)];
            *(bf16x8*)&H[(size_t)grow * 128 + h * 64 + c8 * 8] = v;
        }
    }
}

// ---------------------------------------------------------------- GEMM2 (half-N)
__global__ __launch_bounds__(256, 4) void gemm2_kernel(const u16* __restrict__ H,
        const u16* __restrict__ img2, const float* __restrict__ feats,
        float* __restrict__ out, int n, int nrb) {
    __shared__ __align__(16) char smem[64 * 140 * 4];   // 35840 B
    u16* w2t = (u16*)smem;
    float* zbuf = (float*)smem;
    int h = blockIdx.x >= nrb;
    int rb = blockIdx.x - (h ? nrb : 0);
    int tid = threadIdx.x;

    const uint4* src = (const uint4*)(img2 + (h << 14));
    uint4* dst = (uint4*)w2t;
#pragma unroll
    for (int i = 0; i < 8; i++) dst[i * 256 + tid] = src[i * 256 + tid];

    int wave = tid >> 6, lane = tid & 63, m16 = lane & 15, quad = lane >> 4;
    int row_a = rb * 64 + wave * 16 + m16;
    int ra = min(row_a, n - 1);
    const u16* hrow = H + (size_t)ra * 128;
    bf16x8 afr[4];
#pragma unroll
    for (int kk = 0; kk < 4; kk++)
        afr[kk] = *(const bf16x8*)(hrow + kk * 32 + quad * 8);
    __syncthreads();

    f32x4 acc[8];
#pragma unroll
    for (int t = 0; t < 8; t++) acc[t] = (f32x4){0.f, 0.f, 0.f, 0.f};
#pragma unroll
    for (int kk = 0; kk < 4; kk++) {
        int chunk = kk * 4 + quad;
#pragma unroll
        for (int t = 0; t < 8; t++) {
            int nn = t * 16 + m16;
            bf16x8 b = *(const bf16x8*)&w2t[nn * 128 + ((chunk ^ (nn & 7)) << 3)];
            acc[t] = __builtin_amdgcn_mfma_f32_16x16x32_bf16(afr[kk], b, acc[t], 0, 0, 0);
        }
    }
    __syncthreads();   // w2t dead; write logits into zbuf

#pragma unroll
    for (int t = 0; t < 8; t++) {
        int col = t * 16 + m16;
#pragma unroll
        for (int rr = 0; rr < 4; rr++) {
            int row_l = wave * 16 + quad * 4 + rr;
            zbuf[row_l * 140 + col] = acc[t][rr];
        }
    }
    __syncthreads();
#pragma unroll
    for (int i = 0; i < 8; i++) {
        int f = i * 256 + tid;              // 0..2047 float4s
        int row_l = f >> 5, c4 = f & 31;
        int grow = rb * 64 + row_l;
        if (grow < n) {
            f32x4 z = *(const f32x4*)&zbuf[row_l * 140 + c4 * 4];
            size_t o = (size_t)grow * 256 + h * 128 + c4 * 4;
            f32x4 ft = *(const f32x4*)&feats[o];
            f32x4 r;
#pragma unroll
            for (int c = 0; c < 4; c++)
                r[c] = ft[c] / (1.0f + __expf(-z[c]));
            *(f32x4*)&out[o] = r;
        }
    }
}

// ---------------------------------------------------------------- launch
extern "C" void kernel_launch(void* const* d_in, const int* in_sizes, int n_in,
                              void* d_out, int out_size, void* d_ws, size_t ws_size,
                              hipStream_t stream) {
    const float* feats = (const float*)d_in[0];
    const int* coords = (const int*)d_in[1];
    const float* W1 = (const float*)d_in[2];
    const float* W2 = (const float*)d_in[3];
    float* out = (float*)d_out;

    int n = in_sizes[1] / 3;                       // 100000 points

    size_t grid_bytes = (size_t)GD * GD * GD * GC * 2;          // 134,217,728
    size_t P_bytes = (size_t)n * GC * 2;                        //  51,200,000
    size_t H_bytes = (size_t)n * 128 * 2;                       //  25,600,000
    u16* grid = (u16*)d_ws;                                     // never initialized
    u16* grid2 = (u16*)((char*)d_ws + grid_bytes);              // y-pass output
    u16* P = (u16*)((char*)d_ws + 2 * grid_bytes);
    u16* H = (u16*)((char*)d_ws + 2 * grid_bytes + P_bytes);
    int* map = (int*)((char*)d_ws + 2 * grid_bytes + P_bytes + H_bytes);
    u16* img1 = (u16*)((char*)map + (size_t)GD * GD * GD * 4);  // +1 MB
    u16* img2 = img1 + 32768;

    init_map<<<256, 256, 0, stream>>>((uint4*)map);
    prep_weights<<<256, 256, 0, stream>>>(W1, W2, img1, img2);
    build_map<<<(n + 255) / 256, 256, 0, stream>>>(coords, map, n);

    pool_z_gather<<<1024, 256, 0, stream>>>(feats, map, grid);     // z (gather, piped)
    pool_y<<<1024, 256, 0, stream>>>(grid, grid2);                 // y (out of place, piped)
    pool_x_compact<<<1024, 256, 0, stream>>>(grid2, map, P);       // x -> compact (piped)

    int nrb = (n + 63) / 64;
    gemm1_kernel<<<2 * nrb, 256, 0, stream>>>(P, img1, H, n, nrb);
    gemm2_kernel<<<2 * nrb, 256, 0, stream>>>(H, img2, feats, out, n, nrb);
}